// Round 10
// baseline (168.147 us; speedup 1.0000x reference)
//
#include <hip/hip_runtime.h>
#include <stdint.h>

#define B_ 2
#define S_ 2048
#define D_ 1024
#define H_ 16
#define HD_ 64
#define M_TOT (B_*S_)   // 4096

typedef __bf16 bf16;
typedef bf16 bf16x8 __attribute__((ext_vector_type(8)));
typedef float f32x4 __attribute__((ext_vector_type(4)));
typedef float f32x16 __attribute__((ext_vector_type(16)));
typedef unsigned int u32;
typedef unsigned int u32x4v __attribute__((ext_vector_type(4)));

__device__ __forceinline__ void gload_lds16(const void* g, void* l) {
    __builtin_amdgcn_global_load_lds((const __attribute__((address_space(1))) void*)g,
                                     (__attribute__((address_space(3))) void*)l, 16, 0, 0);
}

__device__ __forceinline__ u32 cvtpk_bf16(float lo, float hi) {
    u32 d;
    asm("v_cvt_pk_bf16_f32 %0, %1, %2" : "=v"(d) : "v"(lo), "v"(hi));
    return d;
}

__device__ __forceinline__ float fmax3(float a, float b, float c) {
    return fmaxf(fmaxf(a, b), c);    // clang fuses to v_max3_f32
}

// ---------------- f32 -> bf16 convert ----------------
__global__ __launch_bounds__(256) void cvt_kernel(
    const float* __restrict__ q, const float* __restrict__ k, const float* __restrict__ v,
    const float* __restrict__ wq, const float* __restrict__ wk,
    const float* __restrict__ wv, const float* __restrict__ wo,
    bf16* __restrict__ xq, bf16* __restrict__ xk, bf16* __restrict__ xv,
    bf16* __restrict__ wqb, bf16* __restrict__ wkb, bf16* __restrict__ wvb, bf16* __restrict__ wob)
{
    const float* src; bf16* dst; int n;
    switch (blockIdx.y) {
        case 0: src=q;  dst=xq;  n=M_TOT*D_; break;
        case 1: src=k;  dst=xk;  n=M_TOT*D_; break;
        case 2: src=v;  dst=xv;  n=M_TOT*D_; break;
        case 3: src=wq; dst=wqb; n=D_*D_;    break;
        case 4: src=wk; dst=wkb; n=D_*D_;    break;
        case 5: src=wv; dst=wvb; n=D_*D_;    break;
        default: src=wo; dst=wob; n=D_*D_;   break;
    }
    int i = (blockIdx.x*blockDim.x + threadIdx.x)*8;
    if (i >= n) return;
    const f32x4* s4 = (const f32x4*)(src + i);
    f32x4 a = s4[0], b = s4[1];
    bf16x8 o;
    #pragma unroll
    for (int j = 0; j < 4; ++j) { o[j] = (bf16)a[j]; o[j+4] = (bf16)b[j]; }
    *(bf16x8*)(dst + i) = o;
}

// ---------------- GEMM mainloop: C[128,128] = A[128,K] * W[128,K]^T ----------------
__device__ __forceinline__ void gemm_mainloop(const bf16* __restrict__ A, const bf16* __restrict__ Wt,
                                              int brow, int bcol, bf16* As, bf16* Bs,
                                              f32x4 (&acc)[4][4])
{
    const int tid = threadIdx.x;
    const int l = tid & 63, w = tid >> 6;
    const int wr = w >> 1, wc = w & 1;
    const int lr = l & 15, lq = l >> 4;

    for (int k0 = 0; k0 < D_; k0 += 32) {
        #pragma unroll
        for (int i = 0; i < 2; ++i) {
            int id = i*256 + tid;
            int row = id >> 2, c8 = (id & 3) << 3;
            gload_lds16(A  + (size_t)(brow + row)*D_ + k0 + c8, As + id*8);
            gload_lds16(Wt + (size_t)(bcol + row)*D_ + k0 + c8, Bs + id*8);
        }
        __syncthreads();
        bf16x8 af[4], bf[4];
        #pragma unroll
        for (int m = 0; m < 4; ++m)
            af[m] = *(const bf16x8*)&As[(wr*64 + m*16 + lr)*32 + lq*8];
        #pragma unroll
        for (int n = 0; n < 4; ++n)
            bf[n] = *(const bf16x8*)&Bs[(wc*64 + n*16 + lr)*32 + lq*8];
        #pragma unroll
        for (int m = 0; m < 4; ++m)
            #pragma unroll
            for (int n = 0; n < 4; ++n)
                acc[m][n] = __builtin_amdgcn_mfma_f32_16x16x32_bf16(af[m], bf[n], acc[m][n], 0, 0, 0);
        __syncthreads();
    }
}

// ---------------- QKV projection GEMM (z: 0=Q,1=K,2=V) ----------------
// Epilogue scatters into MFMA-fragment-major layouts (1KB chunks, lane-ordered):
//  Q/K: chunk=(s>>5)*4+(hd>>4), lane=((hd>>3)&1)<<5 | (s&31), j=hd&7
//  V:   chunk=(s>>6)*8+((s>>4)&3)*2+(hd>>5), lane=((s>>3)&1)<<5 | (hd&31), j=s&7
__global__ __launch_bounds__(256) void gemm_qkv(
    const bf16* __restrict__ xq, const bf16* __restrict__ xk, const bf16* __restrict__ xv,
    const bf16* __restrict__ wqb, const bf16* __restrict__ wkb, const bf16* __restrict__ wvb,
    const float* __restrict__ bq, const float* __restrict__ bk, const float* __restrict__ bv,
    bf16* __restrict__ Qf, bf16* __restrict__ Kf, bf16* __restrict__ Vf)
{
    __shared__ __align__(16) bf16 As[128*32];
    __shared__ __align__(16) bf16 Bs[128*32];
    const int z = blockIdx.z;
    const bf16* A  = (z==0) ? xq  : (z==1) ? xk  : xv;
    const bf16* Wt = (z==0) ? wqb : (z==1) ? wkb : wvb;
    const float* bias = (z==0) ? bq : (z==1) ? bk : bv;

    const int brow = (blockIdx.x & 31)*128;
    const int bcol = (blockIdx.x >> 5)*128;

    f32x4 acc[4][4] = {};
    gemm_mainloop(A, Wt, brow, bcol, As, Bs, acc);

    const int tid = threadIdx.x;
    const int l = tid & 63, w = tid >> 6;
    const int wr = w >> 1, wc = w & 1;
    const int lr = l & 15, lq = l >> 4;

    #pragma unroll
    for (int m = 0; m < 4; ++m)
        #pragma unroll
        for (int n = 0; n < 4; ++n) {
            int col = bcol + wc*64 + n*16 + lr;
            float bv_ = bias[col];
            int h = col >> 6, hd = col & 63;
            #pragma unroll
            for (int r = 0; r < 4; ++r) {
                int row = brow + wr*64 + m*16 + lq*4 + r;
                int b = row >> 11, s = row & 2047;
                float val = acc[m][n][r] + bv_;
                if (z == 0) val *= 0.18033688011112042f;   // 1/sqrt(64) * log2(e) folded into Q
                size_t hbase = ((size_t)b*H_ + h)*S_*HD_;
                if (z < 2) {
                    int chunk = ((s >> 5) << 2) + (hd >> 4);
                    int lane  = (((hd >> 3) & 1) << 5) | (s & 31);
                    bf16* dst = (z==0) ? Qf : Kf;
                    dst[hbase + (size_t)chunk*512 + lane*8 + (hd & 7)] = (bf16)val;
                } else {
                    int chunk = ((s >> 6) << 3) + (((s >> 4) & 3) << 1) + (hd >> 5);
                    int lane  = (((s >> 3) & 1) << 5) | (hd & 31);
                    Vf[hbase + (size_t)chunk*512 + lane*8 + (s & 7)] = (bf16)val;
                }
            }
        }
}

// ---------------- output projection GEMM ----------------
__global__ __launch_bounds__(256) void gemm_out(
    const bf16* __restrict__ Oat, const bf16* __restrict__ wob,
    const float* __restrict__ bo, float* __restrict__ out)
{
    __shared__ __align__(16) bf16 As[128*32];
    __shared__ __align__(16) bf16 Bs[128*32];
    const int brow = (blockIdx.x & 31)*128;
    const int bcol = (blockIdx.x >> 5)*128;

    f32x4 acc[4][4] = {};
    gemm_mainloop(Oat, wob, brow, bcol, As, Bs, acc);

    const int tid = threadIdx.x;
    const int l = tid & 63, w = tid >> 6;
    const int wr = w >> 1, wc = w & 1;
    const int lr = l & 15, lq = l >> 4;

    #pragma unroll
    for (int m = 0; m < 4; ++m)
        #pragma unroll
        for (int n = 0; n < 4; ++n) {
            int col = bcol + wc*64 + n*16 + lr;
            float bv_ = bo[col];
            #pragma unroll
            for (int r = 0; r < 4; ++r) {
                int row = brow + wr*64 + m*16 + lq*4 + r;
                out[(size_t)row*D_ + col] = acc[m][n][r] + bv_;
            }
        }
}

// ---------------- causal flash attention v9: fully double-buffered K AND V ----------------
// 1 wave per block; 32 q-rows per wave; 64-key tiles, fragment-major coalesced loads.
// Steady state: iteration T consumes ONLY data loaded at iteration T-1 or earlier:
//   CT = scores(T) (QK'd at T-1), VA = V(T) (loaded at T-1), KCUR = K(T+1) (loaded at T-1).
// Iteration: issue V(T+1) loads FIRST, then K(T+2) (so waits for V never drain the K
// prefetch); QK(T+1) [MFMA] || softmax(T) [VALU]; PV(T). Nothing waits on this
// iteration's loads => memory latency gets a full iteration (~700cyc) of slack.
#define PIPE_ITER(CT0, CT1, NT0, NT1, KCUR, KOTH, VA0, VA1, VB0, VB1, T) do {               \
    const int T_ = (T);                                                                     \
    const int kc0_ = T_*64;                                                                 \
    const bool last_ = (T_ == nkt - 1);                                                     \
    if (T_ + 1 < nkt) {   /* V(T+1) -> VB, issued FIRST */                                  \
        _Pragma("unroll")                                                                   \
        for (int c = 0; c < 4; ++c) {                                                       \
            VB0[c] = *(const bf16x8*)(Vfp + (size_t)((T_+1)*8 + c*2 + 0)*512 + l8);         \
            VB1[c] = *(const bf16x8*)(Vfp + (size_t)((T_+1)*8 + c*2 + 1)*512 + l8);         \
        }                                                                                   \
    }                                                                                       \
    if (T_ + 2 < nkt) {   /* K(T+2) -> KOTH, issued after V */                              \
        _Pragma("unroll")                                                                   \
        for (int kv2 = 0; kv2 < 2; ++kv2)                                                   \
            _Pragma("unroll")                                                               \
            for (int dc = 0; dc < 4; ++dc)                                                  \
                KOTH[kv2][dc] = *(const bf16x8*)(Kfp + (size_t)(((T_+2)*2 + kv2)*4 + dc)*512 + l8); \
    }                                                                                       \
    if (T_ + 1 < nkt) {   /* QK(T+1) on registers loaded last iteration */                  \
        NT0 = (f32x16){}; NT1 = (f32x16){};                                                 \
        __builtin_amdgcn_s_setprio(1);                                                      \
        _Pragma("unroll")                                                                   \
        for (int dc = 0; dc < 4; ++dc)                                                      \
            NT0 = __builtin_amdgcn_mfma_f32_32x32x16_bf16(KCUR[0][dc], qb[dc], NT0, 0, 0, 0); \
        _Pragma("unroll")                                                                   \
        for (int dc = 0; dc < 4; ++dc)                                                      \
            NT1 = __builtin_amdgcn_mfma_f32_32x32x16_bf16(KCUR[1][dc], qb[dc], NT1, 0, 0, 0); \
        __builtin_amdgcn_s_setprio(0);                                                      \
    }                                                                                       \
    if (last_) {                                                                            \
        _Pragma("unroll")                                                                   \
        for (int reg = 0; reg < 16; ++reg) {                                                \
            const int rr = (reg & 3) + 8*(reg >> 2) + 4*hi;                                 \
            if (kc0_ + rr > qrow)      CT0[reg] = -1e30f;                                   \
            if (kc0_ + 32 + rr > qrow) CT1[reg] = -1e30f;                                   \
        }                                                                                   \
    }                                                                                       \
    /* row max: max3 tree (32 vals) + one cross-half shuffle */                             \
    float m0 = fmax3(CT0[0], CT0[1], CT0[2]);                                               \
    float m1 = fmax3(CT0[3], CT0[4], CT0[5]);                                               \
    float m2 = fmax3(CT0[6], CT0[7], CT0[8]);                                               \
    float m3 = fmax3(CT0[9], CT0[10], CT0[11]);                                             \
    float m4 = fmax3(CT0[12], CT0[13], CT0[14]);                                            \
    float m5 = fmax3(CT0[15], CT1[0], CT1[1]);                                              \
    float m6 = fmax3(CT1[2], CT1[3], CT1[4]);                                               \
    float m7 = fmax3(CT1[5], CT1[6], CT1[7]);                                               \
    float m8 = fmax3(CT1[8], CT1[9], CT1[10]);                                              \
    float m9 = fmax3(CT1[11], CT1[12], CT1[13]);                                            \
    float ma = fmaxf(CT1[14], CT1[15]);                                                     \
    float mb0 = fmax3(m0, m1, m2), mb1 = fmax3(m3, m4, m5);                                 \
    float mb2 = fmax3(m6, m7, m8), mb3 = fmax3(m9, ma, mb0);                                \
    float vm = fmax3(mb1, mb2, mb3);                                                        \
    vm = fmaxf(vm, __shfl_xor(vm, 32));                                                     \
    if (!__all(vm <= mrun + 8.f)) {                                                         \
        float nm = fmaxf(mrun, vm);                                                         \
        float al = exp2f(mrun - nm);                                                        \
        _Pragma("unroll")                                                                   \
        for (int i = 0; i < 16; ++i) { ot0[i] *= al; ot1[i] *= al; }                        \
        lrun *= al;                                                                         \
        mrun = nm;                                                                          \
    }                                                                                       \
    _Pragma("unroll")                                                                       \
    for (int i = 0; i < 16; ++i) {                                                          \
        CT0[i] = exp2f(CT0[i] - mrun);                                                      \
        CT1[i] = exp2f(CT1[i] - mrun);                                                      \
    }                                                                                       \
    float s8[8];                                                                            \
    _Pragma("unroll")                                                                       \
    for (int i = 0; i < 8; ++i)                                                             \
        s8[i] = (CT0[i] + CT0[i+8]) + (CT1[i] + CT1[i+8]);                                  \
    float s4a = s8[0]+s8[4], s4b = s8[1]+s8[5], s4c = s8[2]+s8[6], s4d = s8[3]+s8[7];       \
    float ps = (s4a + s4b) + (s4c + s4d);                                                   \
    ps += __shfl_xor(ps, 32);                                                               \
    lrun += ps;                                                                             \
    u32 own0[8], own1[8];                                                                   \
    _Pragma("unroll")                                                                       \
    for (int u = 0; u < 8; ++u) {                                                           \
        own0[u] = cvtpk_bf16(CT0[2*u], CT0[2*u+1]);                                         \
        own1[u] = cvtpk_bf16(CT1[2*u], CT1[2*u+1]);                                         \
    }                                                                                       \
    /* hi-dependent send: hi sends own[{0,1,4,5}], lo sends own[{2,3,6,7}] */               \
    u32 rcv0[4], rcv1[4];                                                                   \
    {                                                                                       \
        u32 s0_ = hi ? own0[0] : own0[2];  u32 s1_ = hi ? own0[1] : own0[3];                \
        u32 s2_ = hi ? own0[4] : own0[6];  u32 s3_ = hi ? own0[5] : own0[7];                \
        rcv0[0] = __shfl_xor(s0_, 32); rcv0[1] = __shfl_xor(s1_, 32);                       \
        rcv0[2] = __shfl_xor(s2_, 32); rcv0[3] = __shfl_xor(s3_, 32);                       \
        u32 t0_ = hi ? own1[0] : own1[2];  u32 t1_ = hi ? own1[1] : own1[3];                \
        u32 t2_ = hi ? own1[4] : own1[6];  u32 t3_ = hi ? own1[5] : own1[7];                \
        rcv1[0] = __shfl_xor(t0_, 32); rcv1[1] = __shfl_xor(t1_, 32);                       \
        rcv1[2] = __shfl_xor(t2_, 32); rcv1[3] = __shfl_xor(t3_, 32);                       \
    }                                                                                       \
    __builtin_amdgcn_s_setprio(1);                                                          \
    _Pragma("unroll")                                                                       \
    for (int c = 0; c < 4; ++c) {                                                           \
        const int b0 = 4*(c & 1);                                                           \
        const int p0 = b0 >> 1;                                                             \
        u32 oa, ob, oc, od, ra, rb;                                                         \
        if ((c >> 1) == 0) {                                                                \
            oa = own0[b0]; ob = own0[b0+1]; oc = own0[b0+2]; od = own0[b0+3];               \
            ra = rcv0[p0]; rb = rcv0[p0+1];                                                 \
        } else {                                                                            \
            oa = own1[b0]; ob = own1[b0+1]; oc = own1[b0+2]; od = own1[b0+3];               \
            ra = rcv1[p0]; rb = rcv1[p0+1];                                                 \
        }                                                                                   \
        u32 w0 = hi ? ra : oa;                                                              \
        u32 w1 = hi ? rb : ob;                                                              \
        u32 w2 = hi ? oc : ra;                                                              \
        u32 w3 = hi ? od : rb;                                                              \
        u32x4v pw = { w0, w1, w2, w3 };                                                     \
        bf16x8 pb = __builtin_bit_cast(bf16x8, pw);                                         \
        ot0 = __builtin_amdgcn_mfma_f32_32x32x16_bf16(VA0[c], pb, ot0, 0, 0, 0);            \
        ot1 = __builtin_amdgcn_mfma_f32_32x32x16_bf16(VA1[c], pb, ot1, 0, 0, 0);            \
    }                                                                                       \
    __builtin_amdgcn_s_setprio(0);                                                          \
} while (0)

__global__ __launch_bounds__(64, 2) void attn_kernel(
    const bf16* __restrict__ Qf, const bf16* __restrict__ Kf,
    const bf16* __restrict__ Vf, bf16* __restrict__ Oat)
{
    __shared__ __align__(16) char Osm[32*128];   // epilogue transpose buffer

    const int l = threadIdx.x & 63;
    const int l31 = l & 31, hi = l >> 5;
    const int l8 = l*8;

    // XCD-pinning decode + balanced qt permutation (r7)
    const int id = (int)blockIdx.x;
    const int xcd = id & 7, slot = id >> 3;
    const int bh  = xcd + 8*(slot >> 6);          // 0..31
    const int s6 = slot & 63;
    const int sb = s6 & 31;
    const int g  = ((sb & 7) << 3) | (sb >> 3);
    const int qt = (s6 < 32) ? g : 63 - g;
    const int b = bh >> 4, h = bh & 15;
    const int q0 = qt*32;
    const int qrow = q0 + l31;

    const bf16* Qfp = Qf + (size_t)bh*S_*HD_;
    const bf16* Kfp = Kf + (size_t)bh*S_*HD_;
    const bf16* Vfp = Vf + (size_t)bh*S_*HD_;

    // Q B-frags (col=q=l31, k=d=dc*16+hi*8+j) — coalesced chunk loads
    bf16x8 qb[4];
    #pragma unroll
    for (int dc = 0; dc < 4; ++dc)
        qb[dc] = *(const bf16x8*)(Qfp + (size_t)(((q0 >> 5) << 2) + dc)*512 + l8);

    f32x16 ot0 = {}, ot1 = {};
    float mrun = -1e30f, lrun = 0.f;
    const int nkt = q0/64 + 1;

    // prologue: load K(0) -> ka, V(0) -> vaA, K(1) -> kb; compute scores(0) -> ctA
    bf16x8 ka[2][4], kb[2][4];
    bf16x8 vaA0[4], vaA1[4], vaB0[4], vaB1[4];
    #pragma unroll
    for (int kv2 = 0; kv2 < 2; ++kv2)
        #pragma unroll
        for (int dc = 0; dc < 4; ++dc)
            ka[kv2][dc] = *(const bf16x8*)(Kfp + (size_t)(kv2*4 + dc)*512 + l8);
    #pragma unroll
    for (int c = 0; c < 4; ++c) {
        vaA0[c] = *(const bf16x8*)(Vfp + (size_t)(c*2 + 0)*512 + l8);
        vaA1[c] = *(const bf16x8*)(Vfp + (size_t)(c*2 + 1)*512 + l8);
    }
    if (nkt > 1) {
        #pragma unroll
        for (int kv2 = 0; kv2 < 2; ++kv2)
            #pragma unroll
            for (int dc = 0; dc < 4; ++dc)
                kb[kv2][dc] = *(const bf16x8*)(Kfp + (size_t)((2 + kv2)*4 + dc)*512 + l8);
    }

    f32x16 ctA0 = {}, ctA1 = {}, ctB0 = {}, ctB1 = {};
    #pragma unroll
    for (int dc = 0; dc < 4; ++dc)
        ctA0 = __builtin_amdgcn_mfma_f32_32x32x16_bf16(ka[0][dc], qb[dc], ctA0, 0, 0, 0);
    #pragma unroll
    for (int dc = 0; dc < 4; ++dc)
        ctA1 = __builtin_amdgcn_mfma_f32_32x32x16_bf16(ka[1][dc], qb[dc], ctA1, 0, 0, 0);

    // steady loop: T even: CT=ctA, KCUR=kb (K(T+1)), VA=vaA; buffers swap each iter
    int t = 0;
    for (;;) {
        PIPE_ITER(ctA0, ctA1, ctB0, ctB1, kb, ka, vaA0, vaA1, vaB0, vaB1, t);
        if (++t >= nkt) break;
        PIPE_ITER(ctB0, ctB1, ctA0, ctA1, ka, kb, vaB0, vaB1, vaA0, vaA1, t);
        if (++t >= nkt) break;
    }

    // epilogue: O^T -> LDS transpose -> coalesced store of O rows (bf16)
    const float inv = 1.f / lrun;
    #pragma unroll
    for (int rp = 0; rp < 16; rp += 2) {
        const int d0 = (rp & 3) + 8*(rp >> 2) + 4*hi;        // d within 32-tile
        u32 p0 = cvtpk_bf16(ot0[rp]*inv, ot0[rp+1]*inv);     // d = d0, d0+1
        u32 p1 = cvtpk_bf16(ot1[rp]*inv, ot1[rp+1]*inv);     // d = 32+d0, 32+d0+1
        const int swz = (l31 & 7) << 4;
        *(u32*)(Osm + l31*128 + (( d0*2)        ^ swz)) = p0;
        *(u32*)(Osm + l31*128 + (((32 + d0)*2)  ^ swz)) = p1;
    }
    // single wave: DS ordering within wave is program-order via lgkmcnt
    #pragma unroll
    for (int p = 0; p < 4; ++p) {
        const int row  = p*8 + (l >> 3);
        const int colb = (l & 7)*16;
        u32x4v v = *(const u32x4v*)(Osm + row*128 + (colb ^ ((row & 7) << 4)));
        char* gp = (char*)Oat + (((size_t)(b*S_ + q0 + row)*D_ + h*64)*2) + colb;
        *(u32x4v*)gp = v;
    }
}

extern "C" void kernel_launch(void* const* d_in, const int* in_sizes, int n_in,
                              void* d_out, int out_size, void* d_ws, size_t ws_size,
                              hipStream_t stream) {
    const float* q  = (const float*)d_in[0];
    const float* k  = (const float*)d_in[1];
    const float* v  = (const float*)d_in[2];
    // d_in[3] = mask (causal, hard-coded in attn kernel)
    const float* wq = (const float*)d_in[4];
    const float* bq = (const float*)d_in[5];
    const float* wk = (const float*)d_in[6];
    const float* bk = (const float*)d_in[7];
    const float* wv = (const float*)d_in[8];
    const float* bv = (const float*)d_in[9];
    const float* wo = (const float*)d_in[10];
    const float* bo = (const float*)d_in[11];
    float* out = (float*)d_out;

    char* p = (char*)d_ws;
    const size_t XSZ = (size_t)M_TOT*D_*sizeof(bf16);   // 8 MiB
    const size_t WSZ = (size_t)D_*D_*sizeof(bf16);      // 2 MiB
    bf16* xq  = (bf16*)p; p += XSZ;
    bf16* xk  = (bf16*)p; p += XSZ;
    bf16* xv  = (bf16*)p; p += XSZ;
    bf16* wqb = (bf16*)p; p += WSZ;
    bf16* wkb = (bf16*)p; p += WSZ;
    bf16* wvb = (bf16*)p; p += WSZ;
    bf16* wob = (bf16*)p; p += WSZ;
    bf16* Qf  = (bf16*)p; p += XSZ;
    bf16* Kf  = (bf16*)p; p += XSZ;
    bf16* Vf  = (bf16*)p; p += XSZ;
    bf16* Oat = (bf16*)p; p += XSZ;

    cvt_kernel<<<dim3(2048, 7), 256, 0, stream>>>(q, k, v, wq, wk, wv, wo,
                                                  xq, xk, xv, wqb, wkb, wvb, wob);
    gemm_qkv<<<dim3(256, 1, 3), 256, 0, stream>>>(xq, xk, xv, wqb, wkb, wvb,
                                                  bq, bk, bv, Qf, Kf, Vf);
    attn_kernel<<<2048, 64, 0, stream>>>(Qf, Kf, Vf, Oat);
    gemm_out<<<dim3(256), 256, 0, stream>>>(Oat, wob, bo, out);
}